// Round 1
// baseline (2912.096 us; speedup 1.0000x reference)
//
#include <hip/hip_runtime.h>
#include <hip/hip_bf16.h>
#include <stdint.h>

#define EPS_LN 1e-5f

// ---------------- degree / CSR construction ----------------

__global__ void count_deg_kernel(const int* __restrict__ dst, int E, unsigned* __restrict__ deg) {
    int e = blockIdx.x * blockDim.x + threadIdx.x;
    if (e < E) atomicAdd(&deg[dst[e]], 1u);
}

__global__ void dinv_kernel(const unsigned* __restrict__ deg, float* __restrict__ dinv, int N) {
    int i = blockIdx.x * blockDim.x + threadIdx.x;
    if (i < N) dinv[i] = rsqrtf((float)(deg[i] + 1u));   // +1 for self-loop
}

// single-block exclusive scan over N degree counts -> row_ptr, cursor
__global__ void scan_kernel(const unsigned* __restrict__ deg, unsigned* __restrict__ row_ptr,
                            unsigned* __restrict__ cursor, int N) {
    __shared__ unsigned sums[1024];
    int t = threadIdx.x;
    int chunk = (N + 1023) / 1024;
    int start = t * chunk, end = min(start + chunk, N);
    unsigned local = 0;
    for (int i = start; i < end; ++i) local += deg[i];
    sums[t] = local;
    __syncthreads();
    for (int off = 1; off < 1024; off <<= 1) {
        unsigned v = (t >= off) ? sums[t - off] : 0u;
        __syncthreads();
        sums[t] += v;
        __syncthreads();
    }
    unsigned run = sums[t] - local;  // exclusive prefix
    for (int i = start; i < end; ++i) {
        row_ptr[i] = run; cursor[i] = run; run += deg[i];
    }
    if (t == 1023) row_ptr[N] = sums[1023];
}

__global__ void fill_csr_kernel(const int* __restrict__ src, const int* __restrict__ dst, int E,
                                unsigned* __restrict__ cursor, unsigned* __restrict__ csr_src) {
    int e = blockIdx.x * blockDim.x + threadIdx.x;
    if (e < E) {
        int d = dst[e];
        unsigned pos = atomicAdd(&cursor[d], 1u);
        csr_src[pos] = (unsigned)src[e];
    }
}

// ---------------- aggregation: out[d] = sum_{e: dst=d} norm_e * in[src_e] (+ self loop) ----------------
// one wave per node; VEC floats per lane (CIN = 64*VEC).
// AFF: gathered values are a*s+t (LayerNorm affine of previous layer), factored as s*sum(w*a)+t*sum(w).
// EPI: add bias + leaky relu before store (layer-4 path).
template<int VEC, bool AFF, bool EPI>
__global__ void aggregate_kernel(const float* __restrict__ X, float* __restrict__ out,
                                 const unsigned* __restrict__ row_ptr, const unsigned* __restrict__ csr_src,
                                 const float* __restrict__ dinv,
                                 const float* __restrict__ s_aff, const float* __restrict__ t_aff,
                                 const float* __restrict__ bias, int N) {
    const int CIN = VEC * 64;
    int wave = threadIdx.x >> 6;
    int lane = threadIdx.x & 63;
    int node = blockIdx.x * 4 + wave;
    if (node >= N) return;
    int col = lane * VEC;

    float di = dinv[node];
    float w0 = di * di;                       // self-loop norm
    float acc[VEC];
    {
        const float* xr = X + (size_t)node * CIN + col;
        if constexpr (VEC == 4) {
            float4 v = *reinterpret_cast<const float4*>(xr);
            acc[0] = w0 * v.x; acc[1] = w0 * v.y; acc[2] = w0 * v.z; acc[3] = w0 * v.w;
        } else {
            float2 v = *reinterpret_cast<const float2*>(xr);
            acc[0] = w0 * v.x; acc[1] = w0 * v.y;
        }
    }
    float wsum = w0;
    unsigned e0 = row_ptr[node], e1 = row_ptr[node + 1];
    for (unsigned e = e0; e < e1; ++e) {
        unsigned s = csr_src[e];
        float w = di * dinv[s];
        const float* sr = X + (size_t)s * CIN + col;
        if constexpr (VEC == 4) {
            float4 v = *reinterpret_cast<const float4*>(sr);
            acc[0] += w * v.x; acc[1] += w * v.y; acc[2] += w * v.z; acc[3] += w * v.w;
        } else {
            float2 v = *reinterpret_cast<const float2*>(sr);
            acc[0] += w * v.x; acc[1] += w * v.y;
        }
        wsum += w;
    }

    float res[VEC];
    #pragma unroll
    for (int j = 0; j < VEC; ++j) {
        float z = acc[j];
        if constexpr (AFF) z = s_aff[col + j] * z + t_aff[col + j] * wsum;
        if constexpr (EPI) {
            z += bias[col + j];
            z = z > 0.f ? z : 0.01f * z;
        }
        res[j] = z;
    }
    float* op = out + (size_t)node * CIN + col;
    if constexpr (VEC == 4) {
        *reinterpret_cast<float4*>(op) = make_float4(res[0], res[1], res[2], res[3]);
    } else {
        *reinterpret_cast<float2*>(op) = make_float2(res[0], res[1]);
    }
}

// ---------------- fp32 GEMM: out = Z[M,K] @ W[K,NN]  (BM=BN=64, BK=32, 256 thr, 4x4/thread) ----------------
// IN_AFF: apply per-k affine to Z on load (LayerNorm fold for layer 4).
// EPI: out = leaky_relu(acc + bias[col]); accumulate per-column sum/sumsq for LayerNorm stats.
template<int K, int NN, bool IN_AFF, bool EPI>
__launch_bounds__(256)
__global__ void gemm_kernel(const float* __restrict__ Z, const float* __restrict__ W,
                            const float* __restrict__ bias,
                            const float* __restrict__ s_aff, const float* __restrict__ t_aff,
                            float* __restrict__ out,
                            float* __restrict__ stat_sum, float* __restrict__ stat_sq, int M) {
    __shared__ float As[32][68];
    __shared__ float Bs[32][64];
    __shared__ float s_l[IN_AFF ? K : 1];
    __shared__ float t_l[IN_AFF ? K : 1];

    int tid = threadIdx.x;
    int tx = tid & 15, ty = tid >> 4;
    int rowBase = blockIdx.x * 64;
    int colBase = blockIdx.y * 64;

    if constexpr (IN_AFF) {
        for (int i = tid; i < K; i += 256) { s_l[i] = s_aff[i]; t_l[i] = t_aff[i]; }
        __syncthreads();
    }

    float acc[4][4] = {};

    for (int kt = 0; kt < K / 32; ++kt) {
        #pragma unroll
        for (int i = 0; i < 2; ++i) {
            int idx = tid + i * 256;
            int r = idx >> 3;
            int c4 = (idx & 7) * 4;
            int grow = rowBase + r;
            float4 v = make_float4(0.f, 0.f, 0.f, 0.f);
            if (grow < M)
                v = *reinterpret_cast<const float4*>(&Z[(size_t)grow * K + kt * 32 + c4]);
            if constexpr (IN_AFF) {
                int k0 = kt * 32 + c4;
                v.x = v.x * s_l[k0 + 0] + t_l[k0 + 0];
                v.y = v.y * s_l[k0 + 1] + t_l[k0 + 1];
                v.z = v.z * s_l[k0 + 2] + t_l[k0 + 2];
                v.w = v.w * s_l[k0 + 3] + t_l[k0 + 3];
                if (grow >= M) { v = make_float4(0.f, 0.f, 0.f, 0.f); }
            }
            As[c4 + 0][r] = v.x; As[c4 + 1][r] = v.y; As[c4 + 2][r] = v.z; As[c4 + 3][r] = v.w;
        }
        #pragma unroll
        for (int i = 0; i < 2; ++i) {
            int idx = tid + i * 256;
            int k = idx >> 4;
            int n4 = (idx & 15) * 4;
            *reinterpret_cast<float4*>(&Bs[k][n4]) =
                *reinterpret_cast<const float4*>(&W[(size_t)(kt * 32 + k) * NN + colBase + n4]);
        }
        __syncthreads();
        #pragma unroll
        for (int k = 0; k < 32; ++k) {
            float4 a = *reinterpret_cast<const float4*>(&As[k][ty * 4]);
            float4 b = *reinterpret_cast<const float4*>(&Bs[k][tx * 4]);
            float av[4] = {a.x, a.y, a.z, a.w};
            float bv[4] = {b.x, b.y, b.z, b.w};
            #pragma unroll
            for (int i2 = 0; i2 < 4; ++i2)
                #pragma unroll
                for (int j = 0; j < 4; ++j)
                    acc[i2][j] += av[i2] * bv[j];
        }
        __syncthreads();
    }

    int row0 = rowBase + ty * 4;
    int col0 = colBase + tx * 4;
    if constexpr (EPI) {
        __shared__ float csum[64];
        __shared__ float csq[64];
        if (tid < 64) { csum[tid] = 0.f; csq[tid] = 0.f; }
        __syncthreads();
        float b0 = bias[col0 + 0], b1 = bias[col0 + 1], b2 = bias[col0 + 2], b3 = bias[col0 + 3];
        float psum[4] = {0.f, 0.f, 0.f, 0.f}, psq[4] = {0.f, 0.f, 0.f, 0.f};
        #pragma unroll
        for (int i = 0; i < 4; ++i) {
            int row = row0 + i;
            if (row < M) {
                float v0 = acc[i][0] + b0, v1 = acc[i][1] + b1, v2 = acc[i][2] + b2, v3 = acc[i][3] + b3;
                v0 = v0 > 0.f ? v0 : 0.01f * v0;
                v1 = v1 > 0.f ? v1 : 0.01f * v1;
                v2 = v2 > 0.f ? v2 : 0.01f * v2;
                v3 = v3 > 0.f ? v3 : 0.01f * v3;
                *reinterpret_cast<float4*>(&out[(size_t)row * NN + col0]) = make_float4(v0, v1, v2, v3);
                psum[0] += v0; psum[1] += v1; psum[2] += v2; psum[3] += v3;
                psq[0] += v0 * v0; psq[1] += v1 * v1; psq[2] += v2 * v2; psq[3] += v3 * v3;
            }
        }
        #pragma unroll
        for (int j = 0; j < 4; ++j) {
            atomicAdd(&csum[tx * 4 + j], psum[j]);
            atomicAdd(&csq[tx * 4 + j], psq[j]);
        }
        __syncthreads();
        if (tid < 64) {
            atomicAdd(&stat_sum[colBase + tid], csum[tid]);
            atomicAdd(&stat_sq[colBase + tid], csq[tid]);
        }
    } else {
        #pragma unroll
        for (int i = 0; i < 4; ++i) {
            int row = row0 + i;
            if (row < M)
                *reinterpret_cast<float4*>(&out[(size_t)row * NN + col0]) =
                    make_float4(acc[i][0], acc[i][1], acc[i][2], acc[i][3]);
        }
    }
}

// ---------------- LayerNorm stats finalize: s = g*rsqrt(var+eps), t = be - mu*s ----------------
__global__ void finalize_kernel(const float* __restrict__ g, const float* __restrict__ be,
                                float* __restrict__ stat_sum, float* __restrict__ stat_sq,
                                float* __restrict__ s_arr, float* __restrict__ t_arr,
                                int C, float invN) {
    int i = threadIdx.x;
    if (i < C) {
        float mu = stat_sum[i] * invN;
        float var = stat_sq[i] * invN - mu * mu;
        float rs = rsqrtf(var + EPS_LN);
        float s = g[i] * rs;
        s_arr[i] = s;
        t_arr[i] = be[i] - mu * s;
        stat_sum[i] = 0.f;   // reset for next layer's accumulation
        stat_sq[i] = 0.f;
    }
}

// column stats over A[N][128] (for layer-4 output)
__global__ void col_stats_kernel(const float* __restrict__ A, float* __restrict__ stat_sum,
                                 float* __restrict__ stat_sq, int N) {
    int c = threadIdx.x;  // 128 threads
    int chunk = (N + gridDim.x - 1) / gridDim.x;
    int n0 = blockIdx.x * chunk, n1 = min(n0 + chunk, N);
    float s = 0.f, q = 0.f;
    for (int n = n0; n < n1; ++n) {
        float v = A[(size_t)n * 128 + c];
        s += v; q += v * v;
    }
    atomicAdd(&stat_sum[c], s);
    atomicAdd(&stat_sq[c], q);
}

// ---------------- global mean pool (batch sorted) ----------------
__global__ void pool_kernel(const float* __restrict__ A, const int* __restrict__ batch,
                            const float* __restrict__ s_arr, const float* __restrict__ t_arr,
                            float* __restrict__ psums, float* __restrict__ pcnt, int N) {
    int c = threadIdx.x;  // 128 threads, one per feature
    int n0 = blockIdx.x * 256;
    if (n0 >= N) return;
    int n1 = min(n0 + 256, N);
    float s = s_arr[c], t = t_arr[c];
    float acc = 0.f, cacc = 0.f;
    int curg = -1;
    for (int n = n0; n < n1; ++n) {
        int g = batch[n];
        if (g != curg) {
            if (curg >= 0) {
                atomicAdd(&psums[curg * 128 + c], acc);
                if (c == 0) atomicAdd(&pcnt[curg], cacc);
            }
            acc = 0.f; cacc = 0.f; curg = g;
        }
        float v = A[(size_t)n * 128 + c];
        acc += v * s + t;
        cacc += 1.f;
    }
    if (curg >= 0) {
        atomicAdd(&psums[curg * 128 + c], acc);
        if (c == 0) atomicAdd(&pcnt[curg], cacc);
    }
}

__global__ void divide_kernel(const float* __restrict__ psums, const float* __restrict__ pcnt,
                              float* __restrict__ out) {
    int i = blockIdx.x * blockDim.x + threadIdx.x;
    if (i < 64 * 128) out[i] = psums[i] / fmaxf(pcnt[i >> 7], 1.0f);
}

// ---------------- launch ----------------
extern "C" void kernel_launch(void* const* d_in, const int* in_sizes, int n_in,
                              void* d_out, int out_size, void* d_ws, size_t ws_size,
                              hipStream_t stream) {
    const float* x      = (const float*)d_in[0];
    const float* W_in   = (const float*)d_in[1];
    const float* b_in   = (const float*)d_in[2];
    const float* g_in   = (const float*)d_in[3];
    const float* be_in  = (const float*)d_in[4];
    const float* W_hid  = (const float*)d_in[5];
    const float* b_hid  = (const float*)d_in[6];
    const float* g_hid  = (const float*)d_in[7];
    const float* be_hid = (const float*)d_in[8];
    const float* W_out  = (const float*)d_in[9];
    const float* b_out  = (const float*)d_in[10];
    const float* g_out  = (const float*)d_in[11];
    const float* be_out = (const float*)d_in[12];
    const int*   eidx   = (const int*)d_in[13];
    const int*   batch  = (const int*)d_in[14];
    float* out = (float*)d_out;

    const int N = in_sizes[14];          // 100000
    const int E = in_sizes[13] / 2;      // 3200000
    const int* e_src = eidx;
    const int* e_dst = eidx + E;

    char* ws = (char*)d_ws;
    size_t off = 0;
    auto alloc = [&](size_t bytes) -> void* {
        void* p = ws + off;
        off = (off + bytes + 255) & ~(size_t)255;
        return p;
    };
    float*    Zbuf     = (float*)alloc((size_t)N * 256 * 4);
    float*    Abuf     = (float*)alloc((size_t)N * 256 * 4);
    unsigned* deg      = (unsigned*)alloc((size_t)N * 4);
    float*    dinv     = (float*)alloc((size_t)N * 4);
    unsigned* row_ptr  = (unsigned*)alloc((size_t)(N + 1) * 4);
    unsigned* cursor   = (unsigned*)alloc((size_t)N * 4);
    unsigned* csr_src  = (unsigned*)alloc((size_t)E * 4);
    float*    stat_sum = (float*)alloc(256 * 4);
    float*    stat_sq  = (float*)alloc(256 * 4);
    float*    s_arr    = (float*)alloc(256 * 4);
    float*    t_arr    = (float*)alloc(256 * 4);
    float*    psums    = (float*)alloc(64 * 128 * 4);
    float*    pcnt     = (float*)alloc(64 * 4);

    const float invN = 1.0f / (float)N;

    hipMemsetAsync(deg, 0, (size_t)N * 4, stream);
    hipMemsetAsync(stat_sum, 0, 256 * 4, stream);
    hipMemsetAsync(stat_sq, 0, 256 * 4, stream);
    hipMemsetAsync(psums, 0, 64 * 128 * 4, stream);
    hipMemsetAsync(pcnt, 0, 64 * 4, stream);

    int egrid = (E + 255) / 256;
    count_deg_kernel<<<egrid, 256, 0, stream>>>(e_dst, E, deg);
    dinv_kernel<<<(N + 255) / 256, 256, 0, stream>>>(deg, dinv, N);
    scan_kernel<<<1, 1024, 0, stream>>>(deg, row_ptr, cursor, N);
    fill_csr_kernel<<<egrid, 256, 0, stream>>>(e_src, e_dst, E, cursor, csr_src);

    int aggGrid = (N + 3) / 4;
    dim3 g256(( (N + 63) / 64 ), 4);   // gemm grid for NN=256
    dim3 g128(( (N + 63) / 64 ), 2);   // gemm grid for NN=128

    // Layer 1: z = A_hat x (128-wide), a1 = lrelu(z @ W_in + b_in), stats
    aggregate_kernel<2, false, false><<<aggGrid, 256, 0, stream>>>(
        x, Zbuf, row_ptr, csr_src, dinv, nullptr, nullptr, nullptr, N);
    gemm_kernel<128, 256, false, true><<<g256, 256, 0, stream>>>(
        Zbuf, W_in, b_in, nullptr, nullptr, Abuf, stat_sum, stat_sq, N);
    finalize_kernel<<<1, 256, 0, stream>>>(g_in, be_in, stat_sum, stat_sq, s_arr, t_arr, 256, invN);

    // Layer 2
    aggregate_kernel<4, true, false><<<aggGrid, 256, 0, stream>>>(
        Abuf, Zbuf, row_ptr, csr_src, dinv, s_arr, t_arr, nullptr, N);
    gemm_kernel<256, 256, false, true><<<g256, 256, 0, stream>>>(
        Zbuf, W_hid, b_hid, nullptr, nullptr, Abuf, stat_sum, stat_sq, N);
    finalize_kernel<<<1, 256, 0, stream>>>(g_hid, be_hid, stat_sum, stat_sq, s_arr, t_arr, 256, invN);

    // Layer 3
    aggregate_kernel<4, true, false><<<aggGrid, 256, 0, stream>>>(
        Abuf, Zbuf, row_ptr, csr_src, dinv, s_arr, t_arr, nullptr, N);
    gemm_kernel<256, 256, false, true><<<g256, 256, 0, stream>>>(
        Zbuf, W_hid + 256 * 256, b_hid + 256, nullptr, nullptr, Abuf, stat_sum, stat_sq, N);
    finalize_kernel<<<1, 256, 0, stream>>>(g_hid + 256, be_hid + 256, stat_sum, stat_sq, s_arr, t_arr, 256, invN);

    // Layer 4: h4 = (affine a3) @ W_out  (GEMM first, aggregate at 128)
    gemm_kernel<256, 128, true, false><<<g128, 256, 0, stream>>>(
        Abuf, W_out, nullptr, s_arr, t_arr, Zbuf, nullptr, nullptr, N);
    aggregate_kernel<2, false, true><<<aggGrid, 256, 0, stream>>>(
        Zbuf, Abuf, row_ptr, csr_src, dinv, nullptr, nullptr, b_out, N);
    col_stats_kernel<<<512, 128, 0, stream>>>(Abuf, stat_sum, stat_sq, N);
    finalize_kernel<<<1, 256, 0, stream>>>(g_out, be_out, stat_sum, stat_sq, s_arr, t_arr, 128, invN);

    // Pool
    pool_kernel<<<(N + 255) / 256, 128, 0, stream>>>(Abuf, batch, s_arr, t_arr, psums, pcnt, N);
    divide_kernel<<<(64 * 128 + 255) / 256, 256, 0, stream>>>(psums, pcnt, out);
}

// Round 2
// 2249.640 us; speedup vs baseline: 1.2945x; 1.2945x over previous
//
#include <hip/hip_runtime.h>
#include <stdint.h>

#define EPS_LN 1e-5f

typedef short bf16x8 __attribute__((ext_vector_type(8)));
typedef float f32x4  __attribute__((ext_vector_type(4)));

__device__ __forceinline__ unsigned short f2bf(float f) {
    unsigned u = __float_as_uint(f);
    unsigned r = (u + 0x7fffu + ((u >> 16) & 1u)) >> 16;
    return (unsigned short)r;
}
__device__ __forceinline__ float bf_lo(unsigned u) { return __uint_as_float(u << 16); }
__device__ __forceinline__ float bf_hi(unsigned u) { return __uint_as_float(u & 0xffff0000u); }

__device__ __forceinline__ void async16(void* lds, const void* g) {
    __builtin_amdgcn_global_load_lds(
        (const __attribute__((address_space(1))) unsigned int*)g,
        (__attribute__((address_space(3))) unsigned int*)lds, 16, 0, 0);
}

// ---------------- degree / CSR construction ----------------

__global__ void count_deg_kernel(const int* __restrict__ dst, int E, unsigned* __restrict__ deg) {
    int e = blockIdx.x * blockDim.x + threadIdx.x;
    if (e < E) atomicAdd(&deg[dst[e]], 1u);
}

__global__ void dinv_kernel(const unsigned* __restrict__ deg, float* __restrict__ dinv, int N) {
    int i = blockIdx.x * blockDim.x + threadIdx.x;
    if (i < N) dinv[i] = rsqrtf((float)(deg[i] + 1u));
}

__global__ void scan_kernel(const unsigned* __restrict__ deg, unsigned* __restrict__ row_ptr,
                            unsigned* __restrict__ cursor, int N) {
    __shared__ unsigned sums[1024];
    int t = threadIdx.x;
    int chunk = (N + 1023) / 1024;
    int start = t * chunk, end = min(start + chunk, N);
    unsigned local = 0;
    for (int i = start; i < end; ++i) local += deg[i];
    sums[t] = local;
    __syncthreads();
    for (int off = 1; off < 1024; off <<= 1) {
        unsigned v = (t >= off) ? sums[t - off] : 0u;
        __syncthreads();
        sums[t] += v;
        __syncthreads();
    }
    unsigned run = sums[t] - local;
    for (int i = start; i < end; ++i) {
        row_ptr[i] = run; cursor[i] = run; run += deg[i];
    }
    if (t == 1023) row_ptr[N] = sums[1023];
}

__global__ void fill_csr_kernel(const int* __restrict__ src, const int* __restrict__ dst, int E,
                                unsigned* __restrict__ cursor, unsigned* __restrict__ csr_src) {
    int e = blockIdx.x * blockDim.x + threadIdx.x;
    if (e < E) {
        int d = dst[e];
        unsigned pos = atomicAdd(&cursor[d], 1u);
        csr_src[pos] = (unsigned)src[e];
    }
}

// ---------------- fp32 -> bf16 conversion (pairs) ----------------
__global__ void cvt_bf_kernel(const float* __restrict__ in, unsigned* __restrict__ out, int n2) {
    int i = blockIdx.x * blockDim.x + threadIdx.x;
    if (i < n2) {
        float2 v = *reinterpret_cast<const float2*>(&in[(size_t)i * 2]);
        out[i] = (unsigned)f2bf(v.x) | ((unsigned)f2bf(v.y) << 16);
    }
}

// ---------------- weight prep: Wt[c][k] = bf16(W[k][c]) ----------------
__global__ void prep_wt_kernel(const float* __restrict__ W, unsigned short* __restrict__ Wt,
                               int K, int NN) {
    int idx = blockIdx.x * blockDim.x + threadIdx.x;
    if (idx < K * NN) {
        int k = idx / NN, c = idx % NN;
        Wt[(size_t)c * K + k] = f2bf(W[idx]);
    }
}

// Wt_out[c][k] = bf16(s[k] * W[k][c]) ; W is [256][128]
__global__ void prep_wout_kernel(const float* __restrict__ W, const float* __restrict__ s_arr,
                                 unsigned short* __restrict__ Wt) {
    int idx = blockIdx.x * blockDim.x + threadIdx.x;
    if (idx < 256 * 128) {
        int k = idx >> 7, c = idx & 127;
        Wt[(size_t)c * 256 + k] = f2bf(s_arr[k] * W[idx]);
    }
}

// tW[c] = sum_k t[k]*W[k][c] ; W is [256][128]
__global__ void tw_kernel(const float* __restrict__ W, const float* __restrict__ t_arr,
                          float* __restrict__ tW) {
    int c = threadIdx.x;  // 128
    float acc = 0.f;
    for (int k = 0; k < 256; ++k) acc += t_arr[k] * W[k * 128 + c];
    tW[c] = acc;
}

// ---------------- aggregation over bf16 rows ----------------
// one wave per node, lane covers VEC bf16 cols (CIN = 64*VEC).
// AFF: out = s[col]*sum(w*a) + t[col]*sum(w)   (LayerNorm fold, bf16 out)
// FINAL: out_f32 = lrelu(sum(w*G) + wsum*tW[col] + bias[col])
template<int VEC, bool AFF, bool FINAL>
__global__ void aggregate_bf(const unsigned* __restrict__ X, void* __restrict__ outp,
                             const unsigned* __restrict__ row_ptr, const unsigned* __restrict__ csr_src,
                             const float* __restrict__ dinv,
                             const float* __restrict__ s_aff, const float* __restrict__ t_aff,
                             const float* __restrict__ tW, const float* __restrict__ bias, int N) {
    const int RSU = VEC * 32;  // row stride in uints
    int wave = threadIdx.x >> 6;
    int lane = threadIdx.x & 63;
    int node = blockIdx.x * 4 + wave;
    if (node >= N) return;
    int cu = lane * (VEC / 2);

    float di = dinv[node];
    float w0 = di * di;
    float acc[VEC];
    float wsum = w0;
    {
        const unsigned* xr = X + (size_t)node * RSU + cu;
        if constexpr (VEC == 4) {
            uint2 v = *reinterpret_cast<const uint2*>(xr);
            acc[0] = w0 * bf_lo(v.x); acc[1] = w0 * bf_hi(v.x);
            acc[2] = w0 * bf_lo(v.y); acc[3] = w0 * bf_hi(v.y);
        } else {
            unsigned v = *xr;
            acc[0] = w0 * bf_lo(v); acc[1] = w0 * bf_hi(v);
        }
    }
    unsigned e0 = row_ptr[node], e1 = row_ptr[node + 1];
    for (unsigned e = e0; e < e1; ++e) {
        unsigned s = csr_src[e];
        float w = di * dinv[s];
        const unsigned* sr = X + (size_t)s * RSU + cu;
        if constexpr (VEC == 4) {
            uint2 v = *reinterpret_cast<const uint2*>(sr);
            acc[0] += w * bf_lo(v.x); acc[1] += w * bf_hi(v.x);
            acc[2] += w * bf_lo(v.y); acc[3] += w * bf_hi(v.y);
        } else {
            unsigned v = *sr;
            acc[0] += w * bf_lo(v); acc[1] += w * bf_hi(v);
        }
        wsum += w;
    }

    int col = lane * VEC;
    float z[VEC];
    #pragma unroll
    for (int j = 0; j < VEC; ++j) {
        float f = acc[j];
        if constexpr (AFF) f = s_aff[col + j] * f + t_aff[col + j] * wsum;
        if constexpr (FINAL) {
            f = f + wsum * tW[col + j] + bias[col + j];
            f = f > 0.f ? f : 0.01f * f;
        }
        z[j] = f;
    }
    if constexpr (FINAL) {
        float* of = (float*)outp;
        *reinterpret_cast<float2*>(&of[(size_t)node * (VEC * 64) + col]) = make_float2(z[0], z[1]);
    } else {
        unsigned* ou = (unsigned*)outp;
        if constexpr (VEC == 4) {
            uint2 p;
            p.x = (unsigned)f2bf(z[0]) | ((unsigned)f2bf(z[1]) << 16);
            p.y = (unsigned)f2bf(z[2]) | ((unsigned)f2bf(z[3]) << 16);
            *reinterpret_cast<uint2*>(&ou[(size_t)node * RSU + cu]) = p;
        } else {
            ou[(size_t)node * RSU + cu] = (unsigned)f2bf(z[0]) | ((unsigned)f2bf(z[1]) << 16);
        }
    }
}

// ---------------- bf16 MFMA GEMM: out[M,NN] = Z[M,K] @ Wt^T  (Wt is [NN][K]) ----------------
// 128x128 tile, BK=64, 4 waves (2x2), 16x16x32 MFMA, global_load_lds staging with
// XOR-swizzled source (lds linear; read applies same XOR). EPI: +bias, lrelu, col stats.
template<int K, int NN, bool EPI>
__launch_bounds__(256)
__global__ void gemm_mfma(const unsigned short* __restrict__ Z, const unsigned short* __restrict__ Wt,
                          const float* __restrict__ bias, unsigned short* __restrict__ out,
                          float* __restrict__ stat_sum, float* __restrict__ stat_sq, int M) {
    __shared__ char smem[32768];          // A: [0,16K), B: [16K,32K)
    __shared__ float csum[128], csq[128];

    const int tid = threadIdx.x;
    const int lane = tid & 63;
    const int w = tid >> 6;
    const int wr = (w >> 1) * 64;
    const int wc = (w & 1) * 64;
    const int rowBase = blockIdx.x * 128;
    const int colBase = blockIdx.y * 128;
    const int frow = lane & 15;
    const int kgrp = lane >> 4;

    f32x4 acc[4][4] = {};

    for (int kt = 0; kt < K / 64; ++kt) {
        // stage A-tile (rows of Z) and B-tile (rows of Wt): 16B/lane, pre-swizzled source
        #pragma unroll
        for (int i = 0; i < 4; ++i) {
            int g = (i * 4 + w) * 64 + lane;
            int r = g >> 3;
            int bl = (g & 7) * 16;
            int bg = bl ^ ((r & 7) << 4);
            const char* src = (const char*)Z + (((size_t)(rowBase + r) * K + kt * 64) << 1) + bg;
            async16(&smem[(i * 4 + w) * 1024], src);
        }
        #pragma unroll
        for (int i = 0; i < 4; ++i) {
            int g = (i * 4 + w) * 64 + lane;
            int r = g >> 3;
            int bl = (g & 7) * 16;
            int bg = bl ^ ((r & 7) << 4);
            const char* src = (const char*)Wt + (((size_t)(colBase + r) * K + kt * 64) << 1) + bg;
            async16(&smem[16384 + (i * 4 + w) * 1024], src);
        }
        __syncthreads();
        #pragma unroll
        for (int kk = 0; kk < 2; ++kk) {
            const int kbyte = kk * 64 + kgrp * 16;
            bf16x8 af[4], bfr[4];
            #pragma unroll
            for (int m = 0; m < 4; ++m) {
                int r = wr + m * 16 + frow;
                af[m] = *reinterpret_cast<const bf16x8*>(&smem[r * 128 + (kbyte ^ ((r & 7) << 4))]);
            }
            #pragma unroll
            for (int n = 0; n < 4; ++n) {
                int c = wc + n * 16 + frow;
                bfr[n] = *reinterpret_cast<const bf16x8*>(&smem[16384 + c * 128 + (kbyte ^ ((c & 7) << 4))]);
            }
            #pragma unroll
            for (int m = 0; m < 4; ++m)
                #pragma unroll
                for (int n = 0; n < 4; ++n)
                    acc[m][n] = __builtin_amdgcn_mfma_f32_16x16x32_bf16(af[m], bfr[n], acc[m][n], 0, 0, 0);
        }
        __syncthreads();
    }

    if constexpr (EPI) {
        if (tid < 128) { csum[tid] = 0.f; csq[tid] = 0.f; }
    }
    __syncthreads();

    #pragma unroll
    for (int n = 0; n < 4; ++n) {
        int c_local = wc + n * 16 + frow;
        int col = colBase + c_local;
        float b = 0.f;
        if constexpr (EPI) b = bias[col];
        float ps = 0.f, pq = 0.f;
        #pragma unroll
        for (int m = 0; m < 4; ++m) {
            #pragma unroll
            for (int j = 0; j < 4; ++j) {
                int row = rowBase + wr + m * 16 + kgrp * 4 + j;
                if (row < M) {
                    float f = acc[m][n][j] + b;
                    if constexpr (EPI) f = f > 0.f ? f : 0.01f * f;
                    out[(size_t)row * NN + col] = f2bf(f);
                    ps += f; pq += f * f;
                }
            }
        }
        if constexpr (EPI) {
            atomicAdd(&csum[c_local], ps);
            atomicAdd(&csq[c_local], pq);
        }
    }
    if constexpr (EPI) {
        __syncthreads();
        if (tid < 128) {
            atomicAdd(&stat_sum[colBase + tid], csum[tid]);
            atomicAdd(&stat_sq[colBase + tid], csq[tid]);
        }
    }
}

// ---------------- LayerNorm finalize ----------------
__global__ void finalize_kernel(const float* __restrict__ g, const float* __restrict__ be,
                                float* __restrict__ stat_sum, float* __restrict__ stat_sq,
                                float* __restrict__ s_arr, float* __restrict__ t_arr,
                                int C, float invN) {
    int i = threadIdx.x;
    if (i < C) {
        float mu = stat_sum[i] * invN;
        float var = stat_sq[i] * invN - mu * mu;
        float rs = rsqrtf(var + EPS_LN);
        float s = g[i] * rs;
        s_arr[i] = s;
        t_arr[i] = be[i] - mu * s;
        stat_sum[i] = 0.f;
        stat_sq[i] = 0.f;
    }
}

// column stats over fp32 A[N][128]
__global__ void col_stats_kernel(const float* __restrict__ A, float* __restrict__ stat_sum,
                                 float* __restrict__ stat_sq, int N) {
    int c = threadIdx.x;
    int chunk = (N + gridDim.x - 1) / gridDim.x;
    int n0 = blockIdx.x * chunk, n1 = min(n0 + chunk, N);
    float s = 0.f, q = 0.f;
    for (int n = n0; n < n1; ++n) {
        float v = A[(size_t)n * 128 + c];
        s += v; q += v * v;
    }
    atomicAdd(&stat_sum[c], s);
    atomicAdd(&stat_sq[c], q);
}

// ---------------- global mean pool ----------------
__global__ void pool_kernel(const float* __restrict__ A, const int* __restrict__ batch,
                            const float* __restrict__ s_arr, const float* __restrict__ t_arr,
                            float* __restrict__ psums, float* __restrict__ pcnt, int N) {
    int c = threadIdx.x;  // 128
    int n0 = blockIdx.x * 256;
    if (n0 >= N) return;
    int n1 = min(n0 + 256, N);
    float s = s_arr[c], t = t_arr[c];
    float acc = 0.f, cacc = 0.f;
    int curg = -1;
    for (int n = n0; n < n1; ++n) {
        int g = batch[n];
        if (g != curg) {
            if (curg >= 0) {
                atomicAdd(&psums[curg * 128 + c], acc);
                if (c == 0) atomicAdd(&pcnt[curg], cacc);
            }
            acc = 0.f; cacc = 0.f; curg = g;
        }
        float v = A[(size_t)n * 128 + c];
        acc += v * s + t;
        cacc += 1.f;
    }
    if (curg >= 0) {
        atomicAdd(&psums[curg * 128 + c], acc);
        if (c == 0) atomicAdd(&pcnt[curg], cacc);
    }
}

__global__ void divide_kernel(const float* __restrict__ psums, const float* __restrict__ pcnt,
                              float* __restrict__ out) {
    int i = blockIdx.x * blockDim.x + threadIdx.x;
    if (i < 64 * 128) out[i] = psums[i] / fmaxf(pcnt[i >> 7], 1.0f);
}

// ---------------- launch ----------------
extern "C" void kernel_launch(void* const* d_in, const int* in_sizes, int n_in,
                              void* d_out, int out_size, void* d_ws, size_t ws_size,
                              hipStream_t stream) {
    const float* x      = (const float*)d_in[0];
    const float* W_in   = (const float*)d_in[1];
    const float* b_in   = (const float*)d_in[2];
    const float* g_in   = (const float*)d_in[3];
    const float* be_in  = (const float*)d_in[4];
    const float* W_hid  = (const float*)d_in[5];
    const float* b_hid  = (const float*)d_in[6];
    const float* g_hid  = (const float*)d_in[7];
    const float* be_hid = (const float*)d_in[8];
    const float* W_out  = (const float*)d_in[9];
    const float* b_out  = (const float*)d_in[10];
    const float* g_out  = (const float*)d_in[11];
    const float* be_out = (const float*)d_in[12];
    const int*   eidx   = (const int*)d_in[13];
    const int*   batch  = (const int*)d_in[14];
    float* out = (float*)d_out;

    const int N = in_sizes[14];          // 100000
    const int E = in_sizes[13] / 2;      // 3200000
    const int Npad = ((N + 127) / 128) * 128;
    const int* e_src = eidx;
    const int* e_dst = eidx + E;

    char* ws = (char*)d_ws;
    size_t off = 0;
    auto alloc = [&](size_t bytes) -> void* {
        void* p = ws + off;
        off = (off + bytes + 255) & ~(size_t)255;
        return p;
    };
    char* B1 = (char*)alloc((size_t)Npad * 256 * 2);   // bf16 [Npad][<=256]
    char* B2 = (char*)alloc((size_t)Npad * 256 * 2);   // bf16 [Npad][<=256] / f32 [Npad][128]
    unsigned* deg      = (unsigned*)alloc((size_t)N * 4);
    float*    dinv     = (float*)alloc((size_t)N * 4);
    unsigned* row_ptr  = (unsigned*)alloc((size_t)(N + 1) * 4);
    unsigned* cursor   = (unsigned*)alloc((size_t)N * 4);
    unsigned* csr_src  = (unsigned*)alloc((size_t)E * 4);
    unsigned short* Wt_in  = (unsigned short*)alloc(256 * 128 * 2);
    unsigned short* Wt_h0  = (unsigned short*)alloc(256 * 256 * 2);
    unsigned short* Wt_h1  = (unsigned short*)alloc(256 * 256 * 2);
    unsigned short* Wt_out = (unsigned short*)alloc(128 * 256 * 2);
    float*    tW       = (float*)alloc(128 * 4);
    float*    stat_sum = (float*)alloc(256 * 4);
    float*    stat_sq  = (float*)alloc(256 * 4);
    float*    s_arr    = (float*)alloc(256 * 4);
    float*    t_arr    = (float*)alloc(256 * 4);
    float*    psums    = (float*)alloc(64 * 128 * 4);
    float*    pcnt     = (float*)alloc(64 * 4);

    const float invN = 1.0f / (float)N;

    hipMemsetAsync(deg, 0, (size_t)N * 4, stream);
    hipMemsetAsync(stat_sum, 0, 256 * 4, stream);
    hipMemsetAsync(stat_sq, 0, 256 * 4, stream);
    hipMemsetAsync(psums, 0, 64 * 128 * 4, stream);
    hipMemsetAsync(pcnt, 0, 64 * 4, stream);

    int egrid = (E + 255) / 256;
    count_deg_kernel<<<egrid, 256, 0, stream>>>(e_dst, E, deg);
    dinv_kernel<<<(N + 255) / 256, 256, 0, stream>>>(deg, dinv, N);
    scan_kernel<<<1, 1024, 0, stream>>>(deg, row_ptr, cursor, N);
    fill_csr_kernel<<<egrid, 256, 0, stream>>>(e_src, e_dst, E, cursor, csr_src);

    // x -> bf16 into B2 (as [Npad][128] bf16)
    cvt_bf_kernel<<<(N * 64 + 255) / 256, 256, 0, stream>>>(x, (unsigned*)B2, N * 64);
    // weight prep
    prep_wt_kernel<<<(128 * 256 + 255) / 256, 256, 0, stream>>>(W_in, Wt_in, 128, 256);
    prep_wt_kernel<<<(256 * 256 + 255) / 256, 256, 0, stream>>>(W_hid, Wt_h0, 256, 256);
    prep_wt_kernel<<<(256 * 256 + 255) / 256, 256, 0, stream>>>(W_hid + 65536, Wt_h1, 256, 256);

    const int aggGrid = (N + 3) / 4;
    dim3 gg256(Npad / 128, 2);
    dim3 gg128(Npad / 128, 1);

    // Layer 1: Z1 = A_hat xbf (128-wide) ; a1 = lrelu(Z1 @ W_in + b) ; stats
    aggregate_bf<2, false, false><<<aggGrid, 256, 0, stream>>>(
        (const unsigned*)B2, B1, row_ptr, csr_src, dinv, nullptr, nullptr, nullptr, nullptr, N);
    gemm_mfma<128, 256, true><<<gg256, 256, 0, stream>>>(
        (const unsigned short*)B1, Wt_in, b_in, (unsigned short*)B2, stat_sum, stat_sq, N);
    finalize_kernel<<<1, 256, 0, stream>>>(g_in, be_in, stat_sum, stat_sq, s_arr, t_arr, 256, invN);

    // Layer 2
    aggregate_bf<4, true, false><<<aggGrid, 256, 0, stream>>>(
        (const unsigned*)B2, B1, row_ptr, csr_src, dinv, s_arr, t_arr, nullptr, nullptr, N);
    gemm_mfma<256, 256, true><<<gg256, 256, 0, stream>>>(
        (const unsigned short*)B1, Wt_h0, b_hid, (unsigned short*)B2, stat_sum, stat_sq, N);
    finalize_kernel<<<1, 256, 0, stream>>>(g_hid, be_hid, stat_sum, stat_sq, s_arr, t_arr, 256, invN);

    // Layer 3
    aggregate_bf<4, true, false><<<aggGrid, 256, 0, stream>>>(
        (const unsigned*)B2, B1, row_ptr, csr_src, dinv, s_arr, t_arr, nullptr, nullptr, N);
    gemm_mfma<256, 256, true><<<gg256, 256, 0, stream>>>(
        (const unsigned short*)B1, Wt_h1, b_hid + 256, (unsigned short*)B2, stat_sum, stat_sq, N);
    finalize_kernel<<<1, 256, 0, stream>>>(g_hid + 256, be_hid + 256, stat_sum, stat_sq, s_arr, t_arr, 256, invN);

    // Layer 4: fold LN affine into W_out; G = a3 @ (diag(s)W_out); agg adds wsum*tW + b_out, lrelu
    prep_wout_kernel<<<(256 * 128 + 255) / 256, 256, 0, stream>>>(W_out, s_arr, Wt_out);
    tw_kernel<<<1, 128, 0, stream>>>(W_out, t_arr, tW);
    gemm_mfma<256, 128, false><<<gg128, 256, 0, stream>>>(
        (const unsigned short*)B2, Wt_out, nullptr, (unsigned short*)B1, nullptr, nullptr, N);
    aggregate_bf<2, false, true><<<aggGrid, 256, 0, stream>>>(
        (const unsigned*)B1, B2, row_ptr, csr_src, dinv, nullptr, nullptr, tW, b_out, N);

    col_stats_kernel<<<512, 128, 0, stream>>>((const float*)B2, stat_sum, stat_sq, N);
    finalize_kernel<<<1, 256, 0, stream>>>(g_out, be_out, stat_sum, stat_sq, s_arr, t_arr, 128, invN);

    pool_kernel<<<(N + 255) / 256, 128, 0, stream>>>((const float*)B2, batch, s_arr, t_arr, psums, pcnt, N);
    divide_kernel<<<(64 * 128 + 255) / 256, 256, 0, stream>>>(psums, pcnt, out);
}

// Round 3
// 1342.696 us; speedup vs baseline: 2.1688x; 1.6755x over previous
//
#include <hip/hip_runtime.h>
#include <stdint.h>

#define EPS_LN 1e-5f

typedef short bf16x8 __attribute__((ext_vector_type(8)));
typedef float f32x4  __attribute__((ext_vector_type(4)));

__device__ __forceinline__ unsigned short f2bf(float f) {
    unsigned u = __float_as_uint(f);
    unsigned r = (u + 0x7fffu + ((u >> 16) & 1u)) >> 16;
    return (unsigned short)r;
}
__device__ __forceinline__ float bf_lo(unsigned u) { return __uint_as_float(u << 16); }
__device__ __forceinline__ float bf_hi(unsigned u) { return __uint_as_float(u & 0xffff0000u); }

__device__ __forceinline__ void async16(void* lds, const void* g) {
    __builtin_amdgcn_global_load_lds(
        (const __attribute__((address_space(1))) unsigned int*)g,
        (__attribute__((address_space(3))) unsigned int*)lds, 16, 0, 0);
}

// ---------------- degree / CSR construction ----------------

__global__ void count_deg_kernel(const int* __restrict__ dst, int E, unsigned* __restrict__ deg) {
    int e = blockIdx.x * blockDim.x + threadIdx.x;
    if (e < E) atomicAdd(&deg[dst[e]], 1u);
}

__global__ void dinv_kernel(const unsigned* __restrict__ deg, float* __restrict__ dinv, int N) {
    int i = blockIdx.x * blockDim.x + threadIdx.x;
    if (i < N) dinv[i] = rsqrtf((float)(deg[i] + 1u));
}

// multi-block scan: (A) per-block sums over 512 elems
__global__ void block_sums_kernel(const unsigned* __restrict__ deg, unsigned* __restrict__ part, int N) {
    __shared__ unsigned s[256];
    int t = threadIdx.x;
    int i0 = blockIdx.x * 512 + t * 2;
    unsigned a = (i0 < N) ? deg[i0] : 0u;
    unsigned b = (i0 + 1 < N) ? deg[i0 + 1] : 0u;
    s[t] = a + b;
    __syncthreads();
    for (int off = 128; off > 0; off >>= 1) {
        if (t < off) s[t] += s[t + off];
        __syncthreads();
    }
    if (t == 0) part[blockIdx.x] = s[0];
}

// (B) single-block exclusive scan of partials (NB <= 256)
__global__ void scan_part_kernel(unsigned* __restrict__ part, unsigned* __restrict__ row_ptr,
                                 int NB, int N) {
    __shared__ unsigned s[256];
    int t = threadIdx.x;
    unsigned v = (t < NB) ? part[t] : 0u;
    s[t] = v;
    __syncthreads();
    for (int off = 1; off < 256; off <<= 1) {
        unsigned u = (t >= off) ? s[t - off] : 0u;
        __syncthreads();
        s[t] += u;
        __syncthreads();
    }
    if (t < NB) part[t] = s[t] - v;      // exclusive
    if (t == 255) row_ptr[N] = s[255];   // total = E
}

// (C) per-block local scan + offset -> row_ptr, cursor
__global__ void scan_blocks_kernel(const unsigned* __restrict__ deg, const unsigned* __restrict__ part,
                                   unsigned* __restrict__ row_ptr, unsigned* __restrict__ cursor, int N) {
    __shared__ unsigned s[256];
    int t = threadIdx.x;
    int i0 = blockIdx.x * 512 + t * 2;
    unsigned a = (i0 < N) ? deg[i0] : 0u;
    unsigned b = (i0 + 1 < N) ? deg[i0 + 1] : 0u;
    unsigned pair = a + b;
    s[t] = pair;
    __syncthreads();
    for (int off = 1; off < 256; off <<= 1) {
        unsigned u = (t >= off) ? s[t - off] : 0u;
        __syncthreads();
        s[t] += u;
        __syncthreads();
    }
    unsigned excl = s[t] - pair + part[blockIdx.x];
    if (i0 < N)     { row_ptr[i0] = excl;         cursor[i0] = excl; }
    if (i0 + 1 < N) { row_ptr[i0 + 1] = excl + a; cursor[i0 + 1] = excl + a; }
}

// fill CSR with fused {src, w = dinv[dst]*dinv[src]} pairs
__global__ void fill_csr_kernel(const int* __restrict__ src, const int* __restrict__ dst,
                                const float* __restrict__ dinv, int E,
                                unsigned* __restrict__ cursor, uint2* __restrict__ csr) {
    int e = blockIdx.x * blockDim.x + threadIdx.x;
    if (e < E) {
        int d = dst[e];
        int s = src[e];
        unsigned pos = atomicAdd(&cursor[d], 1u);
        float w = dinv[d] * dinv[s];
        csr[pos] = make_uint2((unsigned)s, __float_as_uint(w));
    }
}

// ---------------- fp32 -> bf16 conversion (pairs) ----------------
__global__ void cvt_bf_kernel(const float* __restrict__ in, unsigned* __restrict__ out, int n2) {
    int i = blockIdx.x * blockDim.x + threadIdx.x;
    if (i < n2) {
        float2 v = *reinterpret_cast<const float2*>(&in[(size_t)i * 2]);
        out[i] = (unsigned)f2bf(v.x) | ((unsigned)f2bf(v.y) << 16);
    }
}

// ---------------- weight prep: Wt[c][k] = bf16(W[k][c]) ----------------
__global__ void prep_wt_kernel(const float* __restrict__ W, unsigned short* __restrict__ Wt,
                               int K, int NN) {
    int idx = blockIdx.x * blockDim.x + threadIdx.x;
    if (idx < K * NN) {
        int k = idx / NN, c = idx % NN;
        Wt[(size_t)c * K + k] = f2bf(W[idx]);
    }
}

__global__ void prep_wout_kernel(const float* __restrict__ W, const float* __restrict__ s_arr,
                                 unsigned short* __restrict__ Wt) {
    int idx = blockIdx.x * blockDim.x + threadIdx.x;
    if (idx < 256 * 128) {
        int k = idx >> 7, c = idx & 127;
        Wt[(size_t)c * 256 + k] = f2bf(s_arr[k] * W[idx]);
    }
}

__global__ void tw_kernel(const float* __restrict__ W, const float* __restrict__ t_arr,
                          float* __restrict__ tW) {
    int c = threadIdx.x;  // 128
    float acc = 0.f;
    for (int k = 0; k < 256; ++k) acc += t_arr[k] * W[k * 128 + c];
    tW[c] = acc;
}

// ---------------- aggregation over bf16 rows (edge-unrolled x4) ----------------
// one wave per node; lane covers VEC bf16 cols (CIN = 64*VEC).
// AFF: out_bf16 = s[col]*sum(w*a) + t[col]*sum(w)
// FINAL: out_f32 = lrelu(sum(w*G) + wsum*tW[col] + bias[col])
template<int VEC, bool AFF, bool FINAL>
__global__ void aggregate_bf(const unsigned* __restrict__ X, void* __restrict__ outp,
                             const unsigned* __restrict__ row_ptr, const uint2* __restrict__ csr,
                             const float* __restrict__ dinv,
                             const float* __restrict__ s_aff, const float* __restrict__ t_aff,
                             const float* __restrict__ tW, const float* __restrict__ bias, int N) {
    const unsigned RSU = VEC * 32;  // row stride in uints
    int node = blockIdx.x * 4 + (threadIdx.x >> 6);
    if (node >= N) return;
    node = __builtin_amdgcn_readfirstlane(node);
    int lane = threadIdx.x & 63;
    unsigned cu = (unsigned)lane * (VEC / 2);

    float di = dinv[node];
    float w0 = di * di;
    float acc[VEC];
    float wsum = w0;
    {
        const unsigned* xr = X + (size_t)((unsigned)node * RSU + cu);
        if constexpr (VEC == 4) {
            uint2 v = *reinterpret_cast<const uint2*>(xr);
            acc[0] = w0 * bf_lo(v.x); acc[1] = w0 * bf_hi(v.x);
            acc[2] = w0 * bf_lo(v.y); acc[3] = w0 * bf_hi(v.y);
        } else {
            unsigned v = *xr;
            acc[0] = w0 * bf_lo(v); acc[1] = w0 * bf_hi(v);
        }
    }
    unsigned e0 = __builtin_amdgcn_readfirstlane(row_ptr[node]);
    unsigned e1 = __builtin_amdgcn_readfirstlane(row_ptr[node + 1]);
    unsigned e = e0;

    if constexpr (VEC == 4) {
        for (; e + 4 <= e1; e += 4) {
            uint2 p0 = csr[e], p1 = csr[e + 1], p2 = csr[e + 2], p3 = csr[e + 3];
            uint2 v0 = *reinterpret_cast<const uint2*>(X + (size_t)(p0.x * RSU + cu));
            uint2 v1 = *reinterpret_cast<const uint2*>(X + (size_t)(p1.x * RSU + cu));
            uint2 v2 = *reinterpret_cast<const uint2*>(X + (size_t)(p2.x * RSU + cu));
            uint2 v3 = *reinterpret_cast<const uint2*>(X + (size_t)(p3.x * RSU + cu));
            float f0 = __uint_as_float(p0.y), f1 = __uint_as_float(p1.y);
            float f2 = __uint_as_float(p2.y), f3 = __uint_as_float(p3.y);
            acc[0] += f0 * bf_lo(v0.x); acc[1] += f0 * bf_hi(v0.x);
            acc[2] += f0 * bf_lo(v0.y); acc[3] += f0 * bf_hi(v0.y);
            acc[0] += f1 * bf_lo(v1.x); acc[1] += f1 * bf_hi(v1.x);
            acc[2] += f1 * bf_lo(v1.y); acc[3] += f1 * bf_hi(v1.y);
            acc[0] += f2 * bf_lo(v2.x); acc[1] += f2 * bf_hi(v2.x);
            acc[2] += f2 * bf_lo(v2.y); acc[3] += f2 * bf_hi(v2.y);
            acc[0] += f3 * bf_lo(v3.x); acc[1] += f3 * bf_hi(v3.x);
            acc[2] += f3 * bf_lo(v3.y); acc[3] += f3 * bf_hi(v3.y);
            wsum += (f0 + f1) + (f2 + f3);
        }
        for (; e < e1; ++e) {
            uint2 p = csr[e];
            uint2 v = *reinterpret_cast<const uint2*>(X + (size_t)(p.x * RSU + cu));
            float f = __uint_as_float(p.y);
            acc[0] += f * bf_lo(v.x); acc[1] += f * bf_hi(v.x);
            acc[2] += f * bf_lo(v.y); acc[3] += f * bf_hi(v.y);
            wsum += f;
        }
    } else {
        for (; e + 4 <= e1; e += 4) {
            uint2 p0 = csr[e], p1 = csr[e + 1], p2 = csr[e + 2], p3 = csr[e + 3];
            unsigned v0 = X[(size_t)(p0.x * RSU + cu)];
            unsigned v1 = X[(size_t)(p1.x * RSU + cu)];
            unsigned v2 = X[(size_t)(p2.x * RSU + cu)];
            unsigned v3 = X[(size_t)(p3.x * RSU + cu)];
            float f0 = __uint_as_float(p0.y), f1 = __uint_as_float(p1.y);
            float f2 = __uint_as_float(p2.y), f3 = __uint_as_float(p3.y);
            acc[0] += f0 * bf_lo(v0); acc[1] += f0 * bf_hi(v0);
            acc[0] += f1 * bf_lo(v1); acc[1] += f1 * bf_hi(v1);
            acc[0] += f2 * bf_lo(v2); acc[1] += f2 * bf_hi(v2);
            acc[0] += f3 * bf_lo(v3); acc[1] += f3 * bf_hi(v3);
            wsum += (f0 + f1) + (f2 + f3);
        }
        for (; e < e1; ++e) {
            uint2 p = csr[e];
            unsigned v = X[(size_t)(p.x * RSU + cu)];
            float f = __uint_as_float(p.y);
            acc[0] += f * bf_lo(v); acc[1] += f * bf_hi(v);
            wsum += f;
        }
    }

    int col = lane * VEC;
    float z[VEC];
    #pragma unroll
    for (int j = 0; j < VEC; ++j) {
        float f = acc[j];
        if constexpr (AFF) f = s_aff[col + j] * f + t_aff[col + j] * wsum;
        if constexpr (FINAL) {
            f = f + wsum * tW[col + j] + bias[col + j];
            f = f > 0.f ? f : 0.01f * f;
        }
        z[j] = f;
    }
    if constexpr (FINAL) {
        float* of = (float*)outp;
        *reinterpret_cast<float2*>(&of[(size_t)node * (VEC * 64) + col]) = make_float2(z[0], z[1]);
    } else {
        unsigned* ou = (unsigned*)outp;
        if constexpr (VEC == 4) {
            uint2 p;
            p.x = (unsigned)f2bf(z[0]) | ((unsigned)f2bf(z[1]) << 16);
            p.y = (unsigned)f2bf(z[2]) | ((unsigned)f2bf(z[3]) << 16);
            *reinterpret_cast<uint2*>(&ou[(size_t)((unsigned)node * RSU + cu)]) = p;
        } else {
            ou[(size_t)((unsigned)node * RSU + cu)] = (unsigned)f2bf(z[0]) | ((unsigned)f2bf(z[1]) << 16);
        }
    }
}

// ---------------- bf16 MFMA GEMM: out[M,NN] = Z[M,K] @ Wt^T  (Wt is [NN][K]) ----------------
template<int K, int NN, bool EPI>
__launch_bounds__(256)
__global__ void gemm_mfma(const unsigned short* __restrict__ Z, const unsigned short* __restrict__ Wt,
                          const float* __restrict__ bias, unsigned short* __restrict__ out,
                          float* __restrict__ stat_sum, float* __restrict__ stat_sq, int M) {
    __shared__ char smem[32768];          // A: [0,16K), B: [16K,32K)
    __shared__ float csum[128], csq[128];

    const int tid = threadIdx.x;
    const int lane = tid & 63;
    const int w = tid >> 6;
    const int wr = (w >> 1) * 64;
    const int wc = (w & 1) * 64;
    const int rowBase = blockIdx.x * 128;
    const int colBase = blockIdx.y * 128;
    const int frow = lane & 15;
    const int kgrp = lane >> 4;

    f32x4 acc[4][4] = {};

    for (int kt = 0; kt < K / 64; ++kt) {
        #pragma unroll
        for (int i = 0; i < 4; ++i) {
            int g = (i * 4 + w) * 64 + lane;
            int r = g >> 3;
            int bl = (g & 7) * 16;
            int bg = bl ^ ((r & 7) << 4);
            const char* src = (const char*)Z + (((size_t)(rowBase + r) * K + kt * 64) << 1) + bg;
            async16(&smem[(i * 4 + w) * 1024], src);
        }
        #pragma unroll
        for (int i = 0; i < 4; ++i) {
            int g = (i * 4 + w) * 64 + lane;
            int r = g >> 3;
            int bl = (g & 7) * 16;
            int bg = bl ^ ((r & 7) << 4);
            const char* src = (const char*)Wt + (((size_t)(colBase + r) * K + kt * 64) << 1) + bg;
            async16(&smem[16384 + (i * 4 + w) * 1024], src);
        }
        __syncthreads();
        #pragma unroll
        for (int kk = 0; kk < 2; ++kk) {
            const int kbyte = kk * 64 + kgrp * 16;
            bf16x8 af[4], bfr[4];
            #pragma unroll
            for (int m = 0; m < 4; ++m) {
                int r = wr + m * 16 + frow;
                af[m] = *reinterpret_cast<const bf16x8*>(&smem[r * 128 + (kbyte ^ ((r & 7) << 4))]);
            }
            #pragma unroll
            for (int n = 0; n < 4; ++n) {
                int c = wc + n * 16 + frow;
                bfr[n] = *reinterpret_cast<const bf16x8*>(&smem[16384 + c * 128 + (kbyte ^ ((c & 7) << 4))]);
            }
            #pragma unroll
            for (int m = 0; m < 4; ++m)
                #pragma unroll
                for (int n = 0; n < 4; ++n)
                    acc[m][n] = __builtin_amdgcn_mfma_f32_16x16x32_bf16(af[m], bfr[n], acc[m][n], 0, 0, 0);
        }
        __syncthreads();
    }

    if constexpr (EPI) {
        if (tid < 128) { csum[tid] = 0.f; csq[tid] = 0.f; }
    }
    __syncthreads();

    #pragma unroll
    for (int n = 0; n < 4; ++n) {
        int c_local = wc + n * 16 + frow;
        int col = colBase + c_local;
        float b = 0.f;
        if constexpr (EPI) b = bias[col];
        float ps = 0.f, pq = 0.f;
        #pragma unroll
        for (int m = 0; m < 4; ++m) {
            #pragma unroll
            for (int j = 0; j < 4; ++j) {
                int row = rowBase + wr + m * 16 + kgrp * 4 + j;
                if (row < M) {
                    float f = acc[m][n][j] + b;
                    if constexpr (EPI) f = f > 0.f ? f : 0.01f * f;
                    out[(size_t)row * NN + col] = f2bf(f);
                    ps += f; pq += f * f;
                }
            }
        }
        if constexpr (EPI) {
            atomicAdd(&csum[c_local], ps);
            atomicAdd(&csq[c_local], pq);
        }
    }
    if constexpr (EPI) {
        __syncthreads();
        if (tid < 128) {
            atomicAdd(&stat_sum[colBase + tid], csum[tid]);
            atomicAdd(&stat_sq[colBase + tid], csq[tid]);
        }
    }
}

// ---------------- LayerNorm finalize ----------------
__global__ void finalize_kernel(const float* __restrict__ g, const float* __restrict__ be,
                                float* __restrict__ stat_sum, float* __restrict__ stat_sq,
                                float* __restrict__ s_arr, float* __restrict__ t_arr,
                                int C, float invN) {
    int i = threadIdx.x;
    if (i < C) {
        float mu = stat_sum[i] * invN;
        float var = stat_sq[i] * invN - mu * mu;
        float rs = rsqrtf(var + EPS_LN);
        float s = g[i] * rs;
        s_arr[i] = s;
        t_arr[i] = be[i] - mu * s;
        stat_sum[i] = 0.f;
        stat_sq[i] = 0.f;
    }
}

// ---------------- fused column stats + raw graph pool over fp32 A[N][128] ----------------
__global__ void stats_pool_kernel(const float* __restrict__ A, const int* __restrict__ batch,
                                  float* __restrict__ stat_sum, float* __restrict__ stat_sq,
                                  float* __restrict__ psums, float* __restrict__ pcnt, int N) {
    int c = threadIdx.x;  // 128
    int n0 = blockIdx.x * 256;
    if (n0 >= N) return;
    int n1 = min(n0 + 256, N);
    float cs = 0.f, cq = 0.f;
    float acc = 0.f, cacc = 0.f;
    int curg = -1;
    for (int n = n0; n < n1; ++n) {
        float v = A[(size_t)n * 128 + c];
        cs += v; cq += v * v;
        int g = batch[n];
        if (g != curg) {
            if (curg >= 0) {
                atomicAdd(&psums[curg * 128 + c], acc);
                if (c == 0) atomicAdd(&pcnt[curg], cacc);
            }
            acc = 0.f; cacc = 0.f; curg = g;
        }
        acc += v;
        cacc += 1.f;
    }
    if (curg >= 0) {
        atomicAdd(&psums[curg * 128 + c], acc);
        if (c == 0) atomicAdd(&pcnt[curg], cacc);
    }
    atomicAdd(&stat_sum[c], cs);
    atomicAdd(&stat_sq[c], cq);
}

// out = s*(psum/cnt) + t  (LN affine applied post-mean)
__global__ void divide_kernel(const float* __restrict__ psums, const float* __restrict__ pcnt,
                              const float* __restrict__ s_arr, const float* __restrict__ t_arr,
                              float* __restrict__ out) {
    int i = blockIdx.x * blockDim.x + threadIdx.x;
    if (i < 64 * 128) {
        int g = i >> 7, c = i & 127;
        float cnt = pcnt[g];
        out[i] = (cnt > 0.f) ? s_arr[c] * (psums[i] / cnt) + t_arr[c] : 0.f;
    }
}

// ---------------- launch ----------------
extern "C" void kernel_launch(void* const* d_in, const int* in_sizes, int n_in,
                              void* d_out, int out_size, void* d_ws, size_t ws_size,
                              hipStream_t stream) {
    const float* x      = (const float*)d_in[0];
    const float* W_in   = (const float*)d_in[1];
    const float* b_in   = (const float*)d_in[2];
    const float* g_in   = (const float*)d_in[3];
    const float* be_in  = (const float*)d_in[4];
    const float* W_hid  = (const float*)d_in[5];
    const float* b_hid  = (const float*)d_in[6];
    const float* g_hid  = (const float*)d_in[7];
    const float* be_hid = (const float*)d_in[8];
    const float* W_out  = (const float*)d_in[9];
    const float* b_out  = (const float*)d_in[10];
    const float* g_out  = (const float*)d_in[11];
    const float* be_out = (const float*)d_in[12];
    const int*   eidx   = (const int*)d_in[13];
    const int*   batch  = (const int*)d_in[14];
    float* out = (float*)d_out;

    const int N = in_sizes[14];          // 100000
    const int E = in_sizes[13] / 2;      // 3200000
    const int Npad = ((N + 127) / 128) * 128;
    const int NB = (N + 511) / 512;      // scan blocks (<=256)
    const int* e_src = eidx;
    const int* e_dst = eidx + E;

    char* ws = (char*)d_ws;
    size_t off = 0;
    auto alloc = [&](size_t bytes) -> void* {
        void* p = ws + off;
        off = (off + bytes + 255) & ~(size_t)255;
        return p;
    };
    char* B1 = (char*)alloc((size_t)Npad * 256 * 2);   // bf16 [Npad][<=256]
    char* B2 = (char*)alloc((size_t)Npad * 256 * 2);   // bf16 [Npad][<=256] / f32 [Npad][128]
    unsigned* deg      = (unsigned*)alloc((size_t)N * 4);
    float*    dinv     = (float*)alloc((size_t)N * 4);
    unsigned* row_ptr  = (unsigned*)alloc((size_t)(N + 1) * 4);
    unsigned* cursor   = (unsigned*)alloc((size_t)N * 4);
    unsigned* part     = (unsigned*)alloc(256 * 4);
    uint2*    csr      = (uint2*)alloc((size_t)E * 8);
    unsigned short* Wt_in  = (unsigned short*)alloc(256 * 128 * 2);
    unsigned short* Wt_h0  = (unsigned short*)alloc(256 * 256 * 2);
    unsigned short* Wt_h1  = (unsigned short*)alloc(256 * 256 * 2);
    unsigned short* Wt_out = (unsigned short*)alloc(128 * 256 * 2);
    float*    tW       = (float*)alloc(128 * 4);
    float*    stat_sum = (float*)alloc(256 * 4);
    float*    stat_sq  = (float*)alloc(256 * 4);
    float*    s_arr    = (float*)alloc(256 * 4);
    float*    t_arr    = (float*)alloc(256 * 4);
    float*    psums    = (float*)alloc(64 * 128 * 4);
    float*    pcnt     = (float*)alloc(64 * 4);

    const float invN = 1.0f / (float)N;

    hipMemsetAsync(deg, 0, (size_t)N * 4, stream);
    hipMemsetAsync(stat_sum, 0, 256 * 4, stream);
    hipMemsetAsync(stat_sq, 0, 256 * 4, stream);
    hipMemsetAsync(psums, 0, 64 * 128 * 4, stream);
    hipMemsetAsync(pcnt, 0, 64 * 4, stream);

    int egrid = (E + 255) / 256;
    count_deg_kernel<<<egrid, 256, 0, stream>>>(e_dst, E, deg);
    dinv_kernel<<<(N + 255) / 256, 256, 0, stream>>>(deg, dinv, N);
    block_sums_kernel<<<NB, 256, 0, stream>>>(deg, part, N);
    scan_part_kernel<<<1, 256, 0, stream>>>(part, row_ptr, NB, N);
    scan_blocks_kernel<<<NB, 256, 0, stream>>>(deg, part, row_ptr, cursor, N);
    fill_csr_kernel<<<egrid, 256, 0, stream>>>(e_src, e_dst, dinv, E, cursor, csr);

    // x -> bf16 into B2 (as [N][128] bf16)
    cvt_bf_kernel<<<(N * 64 + 255) / 256, 256, 0, stream>>>(x, (unsigned*)B2, N * 64);
    // weight prep
    prep_wt_kernel<<<(128 * 256 + 255) / 256, 256, 0, stream>>>(W_in, Wt_in, 128, 256);
    prep_wt_kernel<<<(256 * 256 + 255) / 256, 256, 0, stream>>>(W_hid, Wt_h0, 256, 256);
    prep_wt_kernel<<<(256 * 256 + 255) / 256, 256, 0, stream>>>(W_hid + 65536, Wt_h1, 256, 256);

    const int aggGrid = (N + 3) / 4;
    dim3 gg256(Npad / 128, 2);
    dim3 gg128(Npad / 128, 1);

    // Layer 1
    aggregate_bf<2, false, false><<<aggGrid, 256, 0, stream>>>(
        (const unsigned*)B2, B1, row_ptr, csr, dinv, nullptr, nullptr, nullptr, nullptr, N);
    gemm_mfma<128, 256, true><<<gg256, 256, 0, stream>>>(
        (const unsigned short*)B1, Wt_in, b_in, (unsigned short*)B2, stat_sum, stat_sq, N);
    finalize_kernel<<<1, 256, 0, stream>>>(g_in, be_in, stat_sum, stat_sq, s_arr, t_arr, 256, invN);

    // Layer 2
    aggregate_bf<4, true, false><<<aggGrid, 256, 0, stream>>>(
        (const unsigned*)B2, B1, row_ptr, csr, dinv, s_arr, t_arr, nullptr, nullptr, N);
    gemm_mfma<256, 256, true><<<gg256, 256, 0, stream>>>(
        (const unsigned short*)B1, Wt_h0, b_hid, (unsigned short*)B2, stat_sum, stat_sq, N);
    finalize_kernel<<<1, 256, 0, stream>>>(g_hid, be_hid, stat_sum, stat_sq, s_arr, t_arr, 256, invN);

    // Layer 3
    aggregate_bf<4, true, false><<<aggGrid, 256, 0, stream>>>(
        (const unsigned*)B2, B1, row_ptr, csr, dinv, s_arr, t_arr, nullptr, nullptr, N);
    gemm_mfma<256, 256, true><<<gg256, 256, 0, stream>>>(
        (const unsigned short*)B1, Wt_h1, b_hid + 256, (unsigned short*)B2, stat_sum, stat_sq, N);
    finalize_kernel<<<1, 256, 0, stream>>>(g_hid + 256, be_hid + 256, stat_sum, stat_sq, s_arr, t_arr, 256, invN);

    // Layer 4
    prep_wout_kernel<<<(256 * 128 + 255) / 256, 256, 0, stream>>>(W_out, s_arr, Wt_out);
    tw_kernel<<<1, 128, 0, stream>>>(W_out, t_arr, tW);
    gemm_mfma<256, 128, false><<<gg128, 256, 0, stream>>>(
        (const unsigned short*)B2, Wt_out, nullptr, (unsigned short*)B1, nullptr, nullptr, N);
    aggregate_bf<2, false, true><<<aggGrid, 256, 0, stream>>>(
        (const unsigned*)B1, B2, row_ptr, csr, dinv, nullptr, nullptr, tW, b_out, N);

    // fused stats + pool, then finalize LN, then affine-after-mean divide
    stats_pool_kernel<<<(N + 255) / 256, 128, 0, stream>>>(
        (const float*)B2, batch, stat_sum, stat_sq, psums, pcnt, N);
    finalize_kernel<<<1, 256, 0, stream>>>(g_out, be_out, stat_sum, stat_sq, s_arr, t_arr, 128, invN);
    divide_kernel<<<(64 * 128 + 255) / 256, 256, 0, stream>>>(psums, pcnt, s_arr, t_arr, out);
}

// Round 4
// 1291.943 us; speedup vs baseline: 2.2540x; 1.0393x over previous
//
#include <hip/hip_runtime.h>
#include <stdint.h>

#define EPS_LN 1e-5f

typedef short bf16x8 __attribute__((ext_vector_type(8)));
typedef float f32x4  __attribute__((ext_vector_type(4)));

__device__ __forceinline__ unsigned short f2bf(float f) {
    unsigned u = __float_as_uint(f);
    unsigned r = (u + 0x7fffu + ((u >> 16) & 1u)) >> 16;
    return (unsigned short)r;
}
__device__ __forceinline__ float bf_lo(unsigned u) { return __uint_as_float(u << 16); }
__device__ __forceinline__ float bf_hi(unsigned u) { return __uint_as_float(u & 0xffff0000u); }

__device__ __forceinline__ void async16(void* lds, const void* g) {
    __builtin_amdgcn_global_load_lds(
        (const __attribute__((address_space(1))) unsigned int*)g,
        (__attribute__((address_space(3))) unsigned int*)lds, 16, 0, 0);
}

// ---------------- degree / CSR construction ----------------

__global__ void count_deg_kernel(const int* __restrict__ dst, int E, unsigned* __restrict__ deg) {
    int e = blockIdx.x * blockDim.x + threadIdx.x;
    if (e < E) atomicAdd(&deg[dst[e]], 1u);
}

__global__ void dinv_kernel(const unsigned* __restrict__ deg, float* __restrict__ dinv, int N) {
    int i = blockIdx.x * blockDim.x + threadIdx.x;
    if (i < N) dinv[i] = rsqrtf((float)(deg[i] + 1u));
}

__global__ void block_sums_kernel(const unsigned* __restrict__ deg, unsigned* __restrict__ part, int N) {
    __shared__ unsigned s[256];
    int t = threadIdx.x;
    int i0 = blockIdx.x * 512 + t * 2;
    unsigned a = (i0 < N) ? deg[i0] : 0u;
    unsigned b = (i0 + 1 < N) ? deg[i0 + 1] : 0u;
    s[t] = a + b;
    __syncthreads();
    for (int off = 128; off > 0; off >>= 1) {
        if (t < off) s[t] += s[t + off];
        __syncthreads();
    }
    if (t == 0) part[blockIdx.x] = s[0];
}

__global__ void scan_part_kernel(unsigned* __restrict__ part, unsigned* __restrict__ row_ptr,
                                 int NB, int N) {
    __shared__ unsigned s[256];
    int t = threadIdx.x;
    unsigned v = (t < NB) ? part[t] : 0u;
    s[t] = v;
    __syncthreads();
    for (int off = 1; off < 256; off <<= 1) {
        unsigned u = (t >= off) ? s[t - off] : 0u;
        __syncthreads();
        s[t] += u;
        __syncthreads();
    }
    if (t < NB) part[t] = s[t] - v;
    if (t == 255) row_ptr[N] = s[255];
}

__global__ void scan_blocks_kernel(const unsigned* __restrict__ deg, const unsigned* __restrict__ part,
                                   unsigned* __restrict__ row_ptr, unsigned* __restrict__ cursor, int N) {
    __shared__ unsigned s[256];
    int t = threadIdx.x;
    int i0 = blockIdx.x * 512 + t * 2;
    unsigned a = (i0 < N) ? deg[i0] : 0u;
    unsigned b = (i0 + 1 < N) ? deg[i0 + 1] : 0u;
    unsigned pair = a + b;
    s[t] = pair;
    __syncthreads();
    for (int off = 1; off < 256; off <<= 1) {
        unsigned u = (t >= off) ? s[t - off] : 0u;
        __syncthreads();
        s[t] += u;
        __syncthreads();
    }
    unsigned excl = s[t] - pair + part[blockIdx.x];
    if (i0 < N)     { row_ptr[i0] = excl;         cursor[i0] = excl; }
    if (i0 + 1 < N) { row_ptr[i0 + 1] = excl + a; cursor[i0 + 1] = excl + a; }
}

__global__ void fill_csr_kernel(const int* __restrict__ src, const int* __restrict__ dst,
                                const float* __restrict__ dinv, int E,
                                unsigned* __restrict__ cursor, uint2* __restrict__ csr) {
    int e = blockIdx.x * blockDim.x + threadIdx.x;
    if (e < E) {
        int d = dst[e];
        int s = src[e];
        unsigned pos = atomicAdd(&cursor[d], 1u);
        float w = dinv[d] * dinv[s];
        csr[pos] = make_uint2((unsigned)s, __float_as_uint(w));
    }
}

// ---------------- fp32 -> bf16 conversion (pairs) ----------------
__global__ void cvt_bf_kernel(const float* __restrict__ in, unsigned* __restrict__ out, int n2) {
    int i = blockIdx.x * blockDim.x + threadIdx.x;
    if (i < n2) {
        float2 v = *reinterpret_cast<const float2*>(&in[(size_t)i * 2]);
        out[i] = (unsigned)f2bf(v.x) | ((unsigned)f2bf(v.y) << 16);
    }
}

// ---------------- weight prep ----------------
__global__ void prep_wt_kernel(const float* __restrict__ W, unsigned short* __restrict__ Wt,
                               int K, int NN) {
    int idx = blockIdx.x * blockDim.x + threadIdx.x;
    if (idx < K * NN) {
        int k = idx / NN, c = idx % NN;
        Wt[(size_t)c * K + k] = f2bf(W[idx]);
    }
}

__global__ void prep_wout_kernel(const float* __restrict__ W, const float* __restrict__ s_arr,
                                 unsigned short* __restrict__ Wt) {
    int idx = blockIdx.x * blockDim.x + threadIdx.x;
    if (idx < 256 * 128) {
        int k = idx >> 7, c = idx & 127;
        Wt[(size_t)c * 256 + k] = f2bf(s_arr[k] * W[idx]);
    }
}

__global__ void tw_kernel(const float* __restrict__ W, const float* __restrict__ t_arr,
                          float* __restrict__ tW) {
    int c = threadIdx.x;  // 128
    float acc = 0.f;
    for (int k = 0; k < 256; ++k) acc += t_arr[k] * W[k * 128 + c];
    tW[c] = acc;
}

// ---------------- aggregation over bf16 rows (edge-unrolled x8) ----------------
template<int VEC, bool AFF, bool FINAL>
__global__ void aggregate_bf(const unsigned* __restrict__ X, void* __restrict__ outp,
                             const unsigned* __restrict__ row_ptr, const uint2* __restrict__ csr,
                             const float* __restrict__ dinv,
                             const float* __restrict__ s_aff, const float* __restrict__ t_aff,
                             const float* __restrict__ tW, const float* __restrict__ bias, int N) {
    const unsigned RSU = VEC * 32;  // row stride in uints
    int node = blockIdx.x * 4 + (threadIdx.x >> 6);
    if (node >= N) return;
    node = __builtin_amdgcn_readfirstlane(node);
    int lane = threadIdx.x & 63;
    unsigned cu = (unsigned)lane * (VEC / 2);

    float di = dinv[node];
    float w0 = di * di;
    float acc[VEC];
    float wsum = w0;
    {
        const unsigned* xr = X + (size_t)((unsigned)node * RSU + cu);
        if constexpr (VEC == 4) {
            uint2 v = *reinterpret_cast<const uint2*>(xr);
            acc[0] = w0 * bf_lo(v.x); acc[1] = w0 * bf_hi(v.x);
            acc[2] = w0 * bf_lo(v.y); acc[3] = w0 * bf_hi(v.y);
        } else {
            unsigned v = *xr;
            acc[0] = w0 * bf_lo(v); acc[1] = w0 * bf_hi(v);
        }
    }
    unsigned e0 = __builtin_amdgcn_readfirstlane(row_ptr[node]);
    unsigned e1 = __builtin_amdgcn_readfirstlane(row_ptr[node + 1]);
    unsigned cnt = e1 - e0;
    unsigned full = cnt & ~7u;

    if constexpr (VEC == 4) {
        for (unsigned i = 0; i < full; i += 8) {
            uint2 p[8];
            #pragma unroll
            for (int u = 0; u < 8; ++u) p[u] = csr[e0 + i + u];
            uint2 v[8];
            #pragma unroll
            for (int u = 0; u < 8; ++u)
                v[u] = *reinterpret_cast<const uint2*>(X + (size_t)(p[u].x * RSU + cu));
            #pragma unroll
            for (int u = 0; u < 8; ++u) {
                float f = __uint_as_float(p[u].y);
                acc[0] += f * bf_lo(v[u].x); acc[1] += f * bf_hi(v[u].x);
                acc[2] += f * bf_lo(v[u].y); acc[3] += f * bf_hi(v[u].y);
                wsum += f;
            }
        }
        for (unsigned i = full; i < cnt; ++i) {
            uint2 p = csr[e0 + i];
            uint2 v = *reinterpret_cast<const uint2*>(X + (size_t)(p.x * RSU + cu));
            float f = __uint_as_float(p.y);
            acc[0] += f * bf_lo(v.x); acc[1] += f * bf_hi(v.x);
            acc[2] += f * bf_lo(v.y); acc[3] += f * bf_hi(v.y);
            wsum += f;
        }
    } else {
        for (unsigned i = 0; i < full; i += 8) {
            uint2 p[8];
            #pragma unroll
            for (int u = 0; u < 8; ++u) p[u] = csr[e0 + i + u];
            unsigned v[8];
            #pragma unroll
            for (int u = 0; u < 8; ++u) v[u] = X[(size_t)(p[u].x * RSU + cu)];
            #pragma unroll
            for (int u = 0; u < 8; ++u) {
                float f = __uint_as_float(p[u].y);
                acc[0] += f * bf_lo(v[u]); acc[1] += f * bf_hi(v[u]);
                wsum += f;
            }
        }
        for (unsigned i = full; i < cnt; ++i) {
            uint2 p = csr[e0 + i];
            unsigned v = X[(size_t)(p.x * RSU + cu)];
            float f = __uint_as_float(p.y);
            acc[0] += f * bf_lo(v); acc[1] += f * bf_hi(v);
            wsum += f;
        }
    }

    int col = lane * VEC;
    float z[VEC];
    #pragma unroll
    for (int j = 0; j < VEC; ++j) {
        float f = acc[j];
        if constexpr (AFF) f = s_aff[col + j] * f + t_aff[col + j] * wsum;
        if constexpr (FINAL) {
            f = f + wsum * tW[col + j] + bias[col + j];
            f = f > 0.f ? f : 0.01f * f;
        }
        z[j] = f;
    }
    if constexpr (FINAL) {
        float* of = (float*)outp;
        *reinterpret_cast<float2*>(&of[(size_t)node * (VEC * 64) + col]) = make_float2(z[0], z[1]);
    } else {
        unsigned* ou = (unsigned*)outp;
        if constexpr (VEC == 4) {
            uint2 p;
            p.x = (unsigned)f2bf(z[0]) | ((unsigned)f2bf(z[1]) << 16);
            p.y = (unsigned)f2bf(z[2]) | ((unsigned)f2bf(z[3]) << 16);
            *reinterpret_cast<uint2*>(&ou[(size_t)((unsigned)node * RSU + cu)]) = p;
        } else {
            ou[(size_t)((unsigned)node * RSU + cu)] = (unsigned)f2bf(z[0]) | ((unsigned)f2bf(z[1]) << 16);
        }
    }
}

// ---------------- bf16 MFMA GEMM: out[M,NN] = Z[M,K] @ Wt^T  (Wt is [NN][K]) ----------------
// Operands SWAPPED in mfma so lane's 4 acc regs = 4 consecutive output COLUMNS:
//   acc[m][n][j] -> out[rowBase+wr+m*16+(lane&15)][colBase+wc+n*16+(lane>>4)*4+j]
template<int K, int NN, bool EPI>
__launch_bounds__(256)
__global__ void gemm_mfma(const unsigned short* __restrict__ Z, const unsigned short* __restrict__ Wt,
                          const float* __restrict__ bias, unsigned short* __restrict__ out,
                          float* __restrict__ stat_sum, float* __restrict__ stat_sq, int M) {
    __shared__ char smem[32768];          // A: [0,16K), B: [16K,32K)
    __shared__ float csum[128], csq[128];

    const int tid = threadIdx.x;
    const int lane = tid & 63;
    const int w = tid >> 6;
    const int wr = (w >> 1) * 64;
    const int wc = (w & 1) * 64;
    const int rowBase = blockIdx.x * 128;
    const int colBase = blockIdx.y * 128;
    const int frow = lane & 15;
    const int kgrp = lane >> 4;

    f32x4 acc[4][4] = {};

    for (int kt = 0; kt < K / 64; ++kt) {
        #pragma unroll
        for (int i = 0; i < 4; ++i) {
            int g = (i * 4 + w) * 64 + lane;
            int r = g >> 3;
            int bl = (g & 7) * 16;
            int bg = bl ^ ((r & 7) << 4);
            const char* src = (const char*)Z + (((size_t)(rowBase + r) * K + kt * 64) << 1) + bg;
            async16(&smem[(i * 4 + w) * 1024], src);
        }
        #pragma unroll
        for (int i = 0; i < 4; ++i) {
            int g = (i * 4 + w) * 64 + lane;
            int r = g >> 3;
            int bl = (g & 7) * 16;
            int bg = bl ^ ((r & 7) << 4);
            const char* src = (const char*)Wt + (((size_t)(colBase + r) * K + kt * 64) << 1) + bg;
            async16(&smem[16384 + (i * 4 + w) * 1024], src);
        }
        __syncthreads();
        #pragma unroll
        for (int kk = 0; kk < 2; ++kk) {
            const int kbyte = kk * 64 + kgrp * 16;
            bf16x8 af[4], bfr[4];
            #pragma unroll
            for (int m = 0; m < 4; ++m) {
                int r = wr + m * 16 + frow;
                af[m] = *reinterpret_cast<const bf16x8*>(&smem[r * 128 + (kbyte ^ ((r & 7) << 4))]);
            }
            #pragma unroll
            for (int n = 0; n < 4; ++n) {
                int c = wc + n * 16 + frow;
                bfr[n] = *reinterpret_cast<const bf16x8*>(&smem[16384 + c * 128 + (kbyte ^ ((c & 7) << 4))]);
            }
            #pragma unroll
            for (int m = 0; m < 4; ++m)
                #pragma unroll
                for (int n = 0; n < 4; ++n)
                    acc[m][n] = __builtin_amdgcn_mfma_f32_16x16x32_bf16(bfr[n], af[m], acc[m][n], 0, 0, 0);
        }
        __syncthreads();
    }

    if constexpr (EPI) {
        if (tid < 128) { csum[tid] = 0.f; csq[tid] = 0.f; }
        __syncthreads();
    }

    #pragma unroll
    for (int n = 0; n < 4; ++n) {
        const int c_local = wc + n * 16 + kgrp * 4;
        const int col = colBase + c_local;
        float4 b4 = make_float4(0.f, 0.f, 0.f, 0.f);
        if constexpr (EPI) b4 = *reinterpret_cast<const float4*>(&bias[col]);
        float ps[4] = {0.f, 0.f, 0.f, 0.f}, pq[4] = {0.f, 0.f, 0.f, 0.f};
        #pragma unroll
        for (int m = 0; m < 4; ++m) {
            int row = rowBase + wr + m * 16 + frow;
            if (row < M) {
                float f0 = acc[m][n][0] + b4.x;
                float f1 = acc[m][n][1] + b4.y;
                float f2 = acc[m][n][2] + b4.z;
                float f3 = acc[m][n][3] + b4.w;
                if constexpr (EPI) {
                    f0 = f0 > 0.f ? f0 : 0.01f * f0;
                    f1 = f1 > 0.f ? f1 : 0.01f * f1;
                    f2 = f2 > 0.f ? f2 : 0.01f * f2;
                    f3 = f3 > 0.f ? f3 : 0.01f * f3;
                }
                uint2 pk;
                pk.x = (unsigned)f2bf(f0) | ((unsigned)f2bf(f1) << 16);
                pk.y = (unsigned)f2bf(f2) | ((unsigned)f2bf(f3) << 16);
                *reinterpret_cast<uint2*>(&out[(size_t)row * NN + col]) = pk;
                if constexpr (EPI) {
                    ps[0] += f0; ps[1] += f1; ps[2] += f2; ps[3] += f3;
                    pq[0] += f0 * f0; pq[1] += f1 * f1; pq[2] += f2 * f2; pq[3] += f3 * f3;
                }
            }
        }
        if constexpr (EPI) {
            // reduce across the 16 frow-lanes (lane bits 0..3), then one atomic per col
            #pragma unroll
            for (int s = 1; s < 16; s <<= 1) {
                #pragma unroll
                for (int j = 0; j < 4; ++j) {
                    ps[j] += __shfl_xor(ps[j], s);
                    pq[j] += __shfl_xor(pq[j], s);
                }
            }
            if (frow == 0) {
                #pragma unroll
                for (int j = 0; j < 4; ++j) {
                    atomicAdd(&csum[c_local + j], ps[j]);
                    atomicAdd(&csq[c_local + j], pq[j]);
                }
            }
        }
    }
    if constexpr (EPI) {
        __syncthreads();
        if (tid < 128) {
            atomicAdd(&stat_sum[colBase + tid], csum[tid]);
            atomicAdd(&stat_sq[colBase + tid], csq[tid]);
        }
    }
}

// ---------------- LayerNorm finalize ----------------
__global__ void finalize_kernel(const float* __restrict__ g, const float* __restrict__ be,
                                float* __restrict__ stat_sum, float* __restrict__ stat_sq,
                                float* __restrict__ s_arr, float* __restrict__ t_arr,
                                int C, float invN) {
    int i = threadIdx.x;
    if (i < C) {
        float mu = stat_sum[i] * invN;
        float var = stat_sq[i] * invN - mu * mu;
        float rs = rsqrtf(var + EPS_LN);
        float s = g[i] * rs;
        s_arr[i] = s;
        t_arr[i] = be[i] - mu * s;
        stat_sum[i] = 0.f;
        stat_sq[i] = 0.f;
    }
}

// ---------------- fused column stats + raw graph pool over fp32 A[N][128] ----------------
__global__ void stats_pool_kernel(const float* __restrict__ A, const int* __restrict__ batch,
                                  float* __restrict__ stat_sum, float* __restrict__ stat_sq,
                                  float* __restrict__ psums, float* __restrict__ pcnt, int N) {
    int c = threadIdx.x;  // 128
    int n0 = blockIdx.x * 256;
    if (n0 >= N) return;
    int n1 = min(n0 + 256, N);
    float cs = 0.f, cq = 0.f;
    float acc = 0.f, cacc = 0.f;
    int curg = -1;
    for (int n = n0; n < n1; ++n) {
        float v = A[(size_t)n * 128 + c];
        cs += v; cq += v * v;
        int g = batch[n];
        if (g != curg) {
            if (curg >= 0) {
                atomicAdd(&psums[curg * 128 + c], acc);
                if (c == 0) atomicAdd(&pcnt[curg], cacc);
            }
            acc = 0.f; cacc = 0.f; curg = g;
        }
        acc += v;
        cacc += 1.f;
    }
    if (curg >= 0) {
        atomicAdd(&psums[curg * 128 + c], acc);
        if (c == 0) atomicAdd(&pcnt[curg], cacc);
    }
    atomicAdd(&stat_sum[c], cs);
    atomicAdd(&stat_sq[c], cq);
}

__global__ void divide_kernel(const float* __restrict__ psums, const float* __restrict__ pcnt,
                              const float* __restrict__ s_arr, const float* __restrict__ t_arr,
                              float* __restrict__ out) {
    int i = blockIdx.x * blockDim.x + threadIdx.x;
    if (i < 64 * 128) {
        int g = i >> 7, c = i & 127;
        float cnt = pcnt[g];
        out[i] = (cnt > 0.f) ? s_arr[c] * (psums[i] / cnt) + t_arr[c] : 0.f;
    }
}

// ---------------- launch ----------------
extern "C" void kernel_launch(void* const* d_in, const int* in_sizes, int n_in,
                              void* d_out, int out_size, void* d_ws, size_t ws_size,
                              hipStream_t stream) {
    const float* x      = (const float*)d_in[0];
    const float* W_in   = (const float*)d_in[1];
    const float* b_in   = (const float*)d_in[2];
    const float* g_in   = (const float*)d_in[3];
    const float* be_in  = (const float*)d_in[4];
    const float* W_hid  = (const float*)d_in[5];
    const float* b_hid  = (const float*)d_in[6];
    const float* g_hid  = (const float*)d_in[7];
    const float* be_hid = (const float*)d_in[8];
    const float* W_out  = (const float*)d_in[9];
    const float* b_out  = (const float*)d_in[10];
    const float* g_out  = (const float*)d_in[11];
    const float* be_out = (const float*)d_in[12];
    const int*   eidx   = (const int*)d_in[13];
    const int*   batch  = (const int*)d_in[14];
    float* out = (float*)d_out;

    const int N = in_sizes[14];          // 100000
    const int E = in_sizes[13] / 2;      // 3200000
    const int Npad = ((N + 127) / 128) * 128;
    const int NB = (N + 511) / 512;      // scan blocks (<=256)
    const int* e_src = eidx;
    const int* e_dst = eidx + E;

    char* ws = (char*)d_ws;
    size_t off = 0;
    auto alloc = [&](size_t bytes) -> void* {
        void* p = ws + off;
        off = (off + bytes + 255) & ~(size_t)255;
        return p;
    };
    char* B1 = (char*)alloc((size_t)Npad * 256 * 2);   // bf16 [Npad][<=256]
    char* B2 = (char*)alloc((size_t)Npad * 256 * 2);   // bf16 [Npad][<=256] / f32 [Npad][128]
    unsigned* deg      = (unsigned*)alloc((size_t)N * 4);
    float*    dinv     = (float*)alloc((size_t)N * 4);
    unsigned* row_ptr  = (unsigned*)alloc((size_t)(N + 1) * 4);
    unsigned* cursor   = (unsigned*)alloc((size_t)N * 4);
    unsigned* part     = (unsigned*)alloc(256 * 4);
    uint2*    csr      = (uint2*)alloc((size_t)E * 8);
    unsigned short* Wt_in  = (unsigned short*)alloc(256 * 128 * 2);
    unsigned short* Wt_h0  = (unsigned short*)alloc(256 * 256 * 2);
    unsigned short* Wt_h1  = (unsigned short*)alloc(256 * 256 * 2);
    unsigned short* Wt_out = (unsigned short*)alloc(128 * 256 * 2);
    float*    tW       = (float*)alloc(128 * 4);
    float*    stat_sum = (float*)alloc(256 * 4);
    float*    stat_sq  = (float*)alloc(256 * 4);
    float*    s_arr    = (float*)alloc(256 * 4);
    float*    t_arr    = (float*)alloc(256 * 4);
    float*    psums    = (float*)alloc(64 * 128 * 4);
    float*    pcnt     = (float*)alloc(64 * 4);

    const float invN = 1.0f / (float)N;

    hipMemsetAsync(deg, 0, (size_t)N * 4, stream);
    hipMemsetAsync(stat_sum, 0, 256 * 4, stream);
    hipMemsetAsync(stat_sq, 0, 256 * 4, stream);
    hipMemsetAsync(psums, 0, 64 * 128 * 4, stream);
    hipMemsetAsync(pcnt, 0, 64 * 4, stream);

    int egrid = (E + 255) / 256;
    count_deg_kernel<<<egrid, 256, 0, stream>>>(e_dst, E, deg);
    dinv_kernel<<<(N + 255) / 256, 256, 0, stream>>>(deg, dinv, N);
    block_sums_kernel<<<NB, 256, 0, stream>>>(deg, part, N);
    scan_part_kernel<<<1, 256, 0, stream>>>(part, row_ptr, NB, N);
    scan_blocks_kernel<<<NB, 256, 0, stream>>>(deg, part, row_ptr, cursor, N);
    fill_csr_kernel<<<egrid, 256, 0, stream>>>(e_src, e_dst, dinv, E, cursor, csr);

    cvt_bf_kernel<<<(N * 64 + 255) / 256, 256, 0, stream>>>(x, (unsigned*)B2, N * 64);
    prep_wt_kernel<<<(128 * 256 + 255) / 256, 256, 0, stream>>>(W_in, Wt_in, 128, 256);
    prep_wt_kernel<<<(256 * 256 + 255) / 256, 256, 0, stream>>>(W_hid, Wt_h0, 256, 256);
    prep_wt_kernel<<<(256 * 256 + 255) / 256, 256, 0, stream>>>(W_hid + 65536, Wt_h1, 256, 256);

    const int aggGrid = (N + 3) / 4;
    dim3 gg256(Npad / 128, 2);
    dim3 gg128(Npad / 128, 1);

    // Layer 1
    aggregate_bf<2, false, false><<<aggGrid, 256, 0, stream>>>(
        (const unsigned*)B2, B1, row_ptr, csr, dinv, nullptr, nullptr, nullptr, nullptr, N);
    gemm_mfma<128, 256, true><<<gg256, 256, 0, stream>>>(
        (const unsigned short*)B1, Wt_in, b_in, (unsigned short*)B2, stat_sum, stat_sq, N);
    finalize_kernel<<<1, 256, 0, stream>>>(g_in, be_in, stat_sum, stat_sq, s_arr, t_arr, 256, invN);

    // Layer 2
    aggregate_bf<4, true, false><<<aggGrid, 256, 0, stream>>>(
        (const unsigned*)B2, B1, row_ptr, csr, dinv, s_arr, t_arr, nullptr, nullptr, N);
    gemm_mfma<256, 256, true><<<gg256, 256, 0, stream>>>(
        (const unsigned short*)B1, Wt_h0, b_hid, (unsigned short*)B2, stat_sum, stat_sq, N);
    finalize_kernel<<<1, 256, 0, stream>>>(g_hid, be_hid, stat_sum, stat_sq, s_arr, t_arr, 256, invN);

    // Layer 3
    aggregate_bf<4, true, false><<<aggGrid, 256, 0, stream>>>(
        (const unsigned*)B2, B1, row_ptr, csr, dinv, s_arr, t_arr, nullptr, nullptr, N);
    gemm_mfma<256, 256, true><<<gg256, 256, 0, stream>>>(
        (const unsigned short*)B1, Wt_h1, b_hid + 256, (unsigned short*)B2, stat_sum, stat_sq, N);
    finalize_kernel<<<1, 256, 0, stream>>>(g_hid + 256, be_hid + 256, stat_sum, stat_sq, s_arr, t_arr, 256, invN);

    // Layer 4
    prep_wout_kernel<<<(256 * 128 + 255) / 256, 256, 0, stream>>>(W_out, s_arr, Wt_out);
    tw_kernel<<<1, 128, 0, stream>>>(W_out, t_arr, tW);
    gemm_mfma<256, 128, false><<<gg128, 256, 0, stream>>>(
        (const unsigned short*)B2, Wt_out, nullptr, (unsigned short*)B1, nullptr, nullptr, N);
    aggregate_bf<2, false, true><<<aggGrid, 256, 0, stream>>>(
        (const unsigned*)B1, B2, row_ptr, csr, dinv, nullptr, nullptr, tW, b_out, N);

    stats_pool_kernel<<<(N + 255) / 256, 128, 0, stream>>>(
        (const float*)B2, batch, stat_sum, stat_sq, psums, pcnt, N);
    finalize_kernel<<<1, 256, 0, stream>>>(g_out, be_out, stat_sum, stat_sq, s_arr, t_arr, 128, invN);
    divide_kernel<<<(64 * 128 + 255) / 256, 256, 0, stream>>>(psums, pcnt, s_arr, t_arr, out);
}